// Round 2
// baseline (1245.793 us; speedup 1.0000x reference)
//
#include <hip/hip_runtime.h>

// SSLMaskingLayer3D: x:(4,96,96,96,32) f32, noise:(4,1728) f32
// out = concat(x_masked, mask) flat, each 113,246,208 f32.
#define NW 1728          // 12*12*12 windows
#define LEN_KEEP 691     // int(1728 * (1.0 - 0.6))
#define XM_ELEMS 113246208LL
#define ROWS 36864       // B*H*W = 4*96*96
#define VEC_PER_ROW 768  // D*C/4 = 96*32/4

// Kernel 1: per-batch stable rank of noise -> window mask (1=masked, 0=kept).
__global__ __launch_bounds__(1024) void win_mask_kernel(
    const float* __restrict__ noise, float* __restrict__ wm) {
    __shared__ float s[NW];
    const int b = blockIdx.x;
    const float* n = noise + b * NW;
    for (int i = threadIdx.x; i < NW; i += blockDim.x) s[i] = n[i];
    __syncthreads();
    for (int w = threadIdx.x; w < NW; w += blockDim.x) {
        const float my = s[w];
        int cnt = 0;
#pragma unroll 4
        for (int j = 0; j < NW; ++j) {
            const float v = s[j];
            // stable argsort rank: strictly-less, or equal with smaller index
            cnt += (v < my) || (v == my && j < w);
        }
        wm[b * NW + w] = (cnt < LEN_KEEP) ? 0.0f : 1.0f;
    }
}

// Kernel 2: streaming apply. One block per (b,h,w) row of D*C = 3072 floats.
__global__ __launch_bounds__(256) void apply_mask_kernel(
    const float4* __restrict__ x, const float* __restrict__ wm,
    float4* __restrict__ xm, float4* __restrict__ mk) {
    const int blk = blockIdx.x;       // b*9216 + h*96 + w
    const int w = blk % 96;
    const int hb = blk / 96;
    const int h = hb % 96;
    const int b = hb / 96;
    const int base_win = b * NW + ((h >> 3) * 12 + (w >> 3)) * 12;
    const long long vbase = (long long)blk * VEC_PER_ROW;
#pragma unroll
    for (int t = threadIdx.x; t < VEC_PER_ROW; t += 256) {
        // 8 float4 per voxel (C=32), 8 voxels per window along D -> t>>6
        const float m = wm[base_win + (t >> 6)];
        const float km = 1.0f - m;
        const float4 xv = x[vbase + t];
        float4 o;
        o.x = xv.x * km; o.y = xv.y * km; o.z = xv.z * km; o.w = xv.w * km;
        xm[vbase + t] = o;
        mk[vbase + t] = make_float4(m, m, m, m);
    }
}

extern "C" void kernel_launch(void* const* d_in, const int* in_sizes, int n_in,
                              void* d_out, int out_size, void* d_ws, size_t ws_size,
                              hipStream_t stream) {
    const float* x = (const float*)d_in[0];
    const float* noise = (const float*)d_in[1];
    float* out = (float*)d_out;
    float* wm = (float*)d_ws;  // 4*1728 floats = 27,648 B

    win_mask_kernel<<<4, 1024, 0, stream>>>(noise, wm);
    apply_mask_kernel<<<ROWS, 256, 0, stream>>>(
        (const float4*)x, wm,
        (float4*)out, (float4*)(out + XM_ELEMS));
}